// Round 4
// baseline (814.480 us; speedup 1.0000x reference)
//
#include <hip/hip_runtime.h>
#include <cstdint>
#include <cstddef>

// ---------- types ----------
typedef __bf16  bf16x8f __attribute__((ext_vector_type(8)));      // MFMA A/B operand (4 VGPRs)
typedef unsigned short u16x8 __attribute__((ext_vector_type(8))); // storage view of 8 bf16
typedef float   f32x16 __attribute__((ext_vector_type(16)));      // MFMA 32x32 C/D operand

__device__ __forceinline__ unsigned short f2bf(float f) {
    union { float f; uint32_t u; } c; c.f = f;
    uint32_t u = c.u;
    return (unsigned short)((u + 0x7fffu + ((u >> 16) & 1u)) >> 16);  // RNE
}

// tanh(x) = 1 - 2/(e^{2x}+1); exact at +/-inf, ~1e-6 abs err
__device__ __forceinline__ float fast_tanh(float x) {
    float e = __builtin_exp2f(2.885390081777927f * x);   // e^{2x}
    return 1.0f - 2.0f * __builtin_amdgcn_rcpf(e + 1.0f);
}

// async 16B global -> LDS (DMA; LDS dest is wave-uniform base + lane*16)
__device__ __forceinline__ void load16_lds(const void* g, unsigned short* l) {
    __builtin_amdgcn_global_load_lds(
        (const __attribute__((address_space(1))) unsigned int*)g,
        (__attribute__((address_space(3))) unsigned int*)l,
        16, 0, 0);
}

// ---------- kernel 0: detect mask storage layout ----------
__global__ __launch_bounds__(256)
void detect_mask(const unsigned char* __restrict__ m, int* __restrict__ flag) {
    __shared__ int s_gt1, s_off;
    if (threadIdx.x == 0) { s_gt1 = 0; s_off = 0; }
    __syncthreads();
    int gt1 = 0, off = 0;
    for (int k = threadIdx.x; k < 4096; k += 256) {
        unsigned char b = m[k];
        if (b > 1) gt1 = 1;
        if ((k & 3) && b) off = 1;
    }
    if (gt1) atomicOr(&s_gt1, 1);
    if (off) atomicOr(&s_off, 1);
    __syncthreads();
    if (threadIdx.x == 0) *flag = (!s_gt1 && s_off) ? 1 : 0;
}

// ---------- kernel 1: cast x fp32 -> bf16 ----------
__global__ __launch_bounds__(256)
void cast_f32_bf16(const float* __restrict__ in, unsigned short* __restrict__ out, int n) {
    int tid = blockIdx.x * blockDim.x + threadIdx.x;
    int stride = gridDim.x * blockDim.x;
    for (int e = tid * 4; e < n; e += stride * 4) {
        float4 v = *(const float4*)(in + e);
        ushort4 o;
        o.x = f2bf(v.x); o.y = f2bf(v.y); o.z = f2bf(v.z); o.w = f2bf(v.w);
        *(ushort4*)(out + e) = o;
    }
}

// ---------- kernel 2: masked weight -> bf16 ----------
__global__ __launch_bounds__(256)
void mask_cast(const float* __restrict__ w, const void* __restrict__ mv,
               const int* __restrict__ flag, unsigned short* __restrict__ out, int n) {
    const bool u8 = (*flag != 0);
    int tid = blockIdx.x * blockDim.x + threadIdx.x;
    int stride = gridDim.x * blockDim.x;
    for (int e = tid * 4; e < n; e += stride * 4) {
        float4 v = *(const float4*)(w + e);
        int m0, m1, m2, m3;
        if (u8) {
            uchar4 mm = *(const uchar4*)((const unsigned char*)mv + e);
            m0 = mm.x; m1 = mm.y; m2 = mm.z; m3 = mm.w;
        } else {
            int4 mm = ((const int4*)mv)[e >> 2];
            m0 = mm.x; m1 = mm.y; m2 = mm.z; m3 = mm.w;
        }
        ushort4 o;
        o.x = m0 ? f2bf(v.x) : (unsigned short)0;
        o.y = m1 ? f2bf(v.y) : (unsigned short)0;
        o.z = m2 ? f2bf(v.z) : (unsigned short)0;
        o.w = m3 ? f2bf(v.w) : (unsigned short)0;
        *(ushort4*)(out + e) = o;
    }
}

// ---------- GEMM: C = tanh(A[M,K] x W[N,K]^T + bias) ----------
// 256x256 tile, BK=32, 512 thr = 8 waves (2Mx4N), per-wave 128x64 out via
// mfma_f32_32x32x16_bf16 (acc[4][2] f32x16). ONE phase per K-tile:
//   [stage tile t+2 -> slot (t+2)%3]  (4 DMA/thread: A 2 + B 2)
//   [s_waitcnt vmcnt(4)]   retires tile t+1's DMA, leaves t+2 in flight
//   [s_barrier]            publishes ALL waves' t+1 DMA before any read
//   [12 ds_read_b128 tile t+1 -> next-phase regs]   (READ-AHEAD)
//   [16 MFMA tile t from regs read LAST phase]      (zero lgkm wait ->
//        MFMA pipe runs while the port drains the read-ahead: the r2/r3
//        port->MFMA serialization (42% util, phase ~= port+MFMA) is broken)
//   [s_barrier]            retire-fence: slot (t+2)%3 overwritten next phase
//                          was last read one phase ago, consumed by MFMA(t+... )
// RAW: tile t+1's DMA (issued phase t-1) retired by vmcnt(4)+barrier before
//      its ds_reads; never vmcnt(0) in the loop. Reads(t+1) retired by the
//      compiler's lgkm wait at MFMA(t+1), before end-barrier(t+1); the slot
//      is re-staged earliest at phase t+2. WAR safe.
// LDS: ring of 3 slots x 32 KB (A 16 KB + B 16 KB) = 96 KB; 1 block/CU.
// Swizzle (measured-clean; pre-applied to GLOBAL src so the linear-dest
// global_load_lds stays legal): rows are 64 B = 4 chunks; chunk ^= (row>>1)&3.
// NOTE r3 finding: SQ_LDS_BANK_CONFLICT = 4.0 cyc/b128 across unrelated
// kernels = inherent b128 port cost, NOT fixable residue. Expect ~2.5e7 still.
// XCD map: by in low 3 bits (197 MB fetch, r2-measured good).
// Epilogue mapping (HW-verified): col=lane&31, row=(reg&3)+8*(reg>>2)+4*(lane>>5).
template <typename OutT, bool FUSE>
__global__ __launch_bounds__(512, 2)
void gemm256(const unsigned short* __restrict__ A,
             const unsigned short* __restrict__ W,
             const float* __restrict__ bias,
             OutT* __restrict__ out,
             const float* __restrict__ w1, const float* __restrict__ b1,
             const float* __restrict__ w2, const float* __restrict__ b2,
             int N, int K, int lbx) {
    // 3 slots x 16384 shorts (A: 8192 | B: 8192) = 96 KiB
    __shared__ __align__(16) unsigned short lds[49152];

    const int t    = threadIdx.x;
    const int lane = t & 63;
    const int wave = t >> 6;
    const int l31  = lane & 31;
    const int lh   = lane >> 5;
    const int wrow = (wave >> 2) * 128;
    const int wcol = (wave & 3) * 64;

    const int id = blockIdx.x;
    const int bx = (id >> 3) & ((1 << lbx) - 1);
    const int by = (id & 7) | ((id >> (3 + lbx)) << 3);
    const int bm = by * 256, bn = bx * 256;

    const char* Au = (const char*)(A + (size_t)bm * K);
    const char* Wu = (const char*)(W + (size_t)bn * K);

    // staging src byte offsets (per thread; identical formula for A and B:
    // both units are 256 rows x 4 chunks of 16 B). chunk u = t + j*512:
    // row r=u>>2, lds chunk c=u&3, global chunk c^((r>>1)&3).
    uint32_t srcOff[2];
#pragma unroll
    for (int j = 0; j < 2; ++j) {
        const int u = t + j * 512, r = u >> 2, c = u & 3;
        srcOff[j] = (uint32_t)((r * K + ((c ^ ((r >> 1) & 3)) << 3)) * 2);
    }

    // fragment read addresses (shorts, slot-relative); q = j*2+lh, ^ (row>>1)&3
    int aAddr[4][2], bAddr[2][2];
#pragma unroll
    for (int mt = 0; mt < 4; ++mt) {
        const int row = wrow + mt * 32 + l31;
#pragma unroll
        for (int j = 0; j < 2; ++j)
            aAddr[mt][j] = row * 32 + (((j * 2 + lh) ^ ((row >> 1) & 3)) << 3);
    }
#pragma unroll
    for (int nt = 0; nt < 2; ++nt) {
        const int row = wcol + nt * 32 + l31;
#pragma unroll
        for (int j = 0; j < 2; ++j)
            bAddr[nt][j] = 8192 + row * 32 + (((j * 2 + lh) ^ ((row >> 1) & 3)) << 3);
    }

#define STAGE(slotS, kB) do {                                                  \
    unsigned short* la_ = lds + (slotS) + t * 8;                               \
    load16_lds(Au + (kB) + srcOff[0], la_);                                    \
    load16_lds(Au + (kB) + srcOff[1], la_ + 4096);                             \
    load16_lds(Wu + (kB) + srcOff[0], la_ + 8192);                             \
    load16_lds(Wu + (kB) + srcOff[1], la_ + 12288);                            \
} while (0)

#define RDAH(FA, FB, base) do {                                                \
    const unsigned short* Lb_ = lds + (base);                                  \
    _Pragma("unroll")                                                          \
    for (int j_ = 0; j_ < 2; ++j_) {                                           \
        _Pragma("unroll")                                                      \
        for (int mt_ = 0; mt_ < 4; ++mt_)                                      \
            FA[mt_][j_] = *(const u16x8*)(Lb_ + aAddr[mt_][j_]);               \
        _Pragma("unroll")                                                      \
        for (int nt_ = 0; nt_ < 2; ++nt_)                                      \
            FB[nt_][j_] = *(const u16x8*)(Lb_ + bAddr[nt_][j_]);               \
    }                                                                          \
} while (0)

#define MM(FA, FB) do {                                                        \
    __builtin_amdgcn_s_setprio(1);                                             \
    _Pragma("unroll")                                                          \
    for (int j_ = 0; j_ < 2; ++j_)                                             \
        _Pragma("unroll")                                                      \
        for (int mt_ = 0; mt_ < 4; ++mt_)                                      \
            _Pragma("unroll")                                                  \
            for (int nt_ = 0; nt_ < 2; ++nt_)                                  \
                acc[mt_][nt_] = __builtin_amdgcn_mfma_f32_32x32x16_bf16(       \
                    __builtin_bit_cast(bf16x8f, FA[mt_][j_]),                  \
                    __builtin_bit_cast(bf16x8f, FB[nt_][j_]),                  \
                    acc[mt_][nt_], 0, 0, 0);                                   \
    __builtin_amdgcn_s_setprio(0);                                             \
} while (0)

#define VMW4 asm volatile("s_waitcnt vmcnt(4)" ::: "memory")
#define BAR  asm volatile("s_barrier" ::: "memory")

    f32x16 acc[4][2] = {};
    u16x8 fa0[4][2], fb0[2][2], fa1[4][2], fb1[2][2];

    // prologue: stage tiles 0,1; retire tile0 (leave tile1 in flight); read
    // tile0 fragments into set0.
    STAGE(0, 0);
    STAGE(16384, 64);
    VMW4;
    BAR;
    RDAH(fa0, fb0, 0);

    // slot rotation (short offsets): at tile t, sRd=(t+1)%3, sSt=(t+2)%3
    uint32_t sOld = 0, sRd = 16384, sSt = 32768;
    const int KBt = K * 2;       // total K bytes per row; tile = 64 B
    const int KL  = KBt - 64;    // last-tile byte offset (stage clamp)
    for (int kb = 0; kb < KBt; kb += 128) {
        int k1 = kb + 128; if (k1 > KL) k1 = KL;   // tile t+2 (even phase)
        int k2 = kb + 192; if (k2 > KL) k2 = KL;   // tile t+2 (odd phase)
        // even phase: MFMA tile kb/64 from set0; read-ahead -> set1
        STAGE(sSt, k1);
        VMW4;
        BAR;
        RDAH(fa1, fb1, sRd);
        MM(fa0, fb0);
        BAR;
        { uint32_t tmp = sOld; sOld = sRd; sRd = sSt; sSt = tmp; }
        // odd phase: MFMA tile kb/64+1 from set1; read-ahead -> set0
        STAGE(sSt, k2);
        VMW4;
        BAR;
        RDAH(fa0, fb0, sRd);
        MM(fa1, fb1);
        BAR;
        { uint32_t tmp = sOld; sOld = sRd; sRd = sSt; sSt = tmp; }
    }
    // drain DMA before LDS dealloc (next block on this CU reuses our LDS)
    asm volatile("s_waitcnt vmcnt(0)" ::: "memory");

    // ---- epilogue ----
    float w10 = 0, w11 = 0, bb1 = 0, w20 = 0, w21 = 0, bb2 = 0;
    if constexpr (FUSE) {
        w10 = w1[0]; w11 = w1[1]; bb1 = b1[0];
        w20 = w2[0]; w21 = w2[1]; bb2 = b2[0];
    }
#pragma unroll
    for (int nt = 0; nt < 2; ++nt) {
        const int gn = bn + wcol + nt * 32 + l31;
        const float bv = bias[gn];
#pragma unroll
        for (int mt = 0; mt < 4; ++mt) {
#pragma unroll
            for (int reg = 0; reg < 16; ++reg) {
                const int gm = bm + wrow + mt * 32 + (reg & 3) + 8 * (reg >> 2) + 4 * lh;
                float c = fast_tanh(acc[mt][nt][reg] + bv);
                if constexpr (FUSE) {
                    float c1 = __shfl_xor(c, 1);
                    float c2 = __shfl_xor(c, 2);
                    float c3 = __shfl_xor(c, 3);
                    float y10 = fast_tanh(w10 * c  + w11 * c1 + bb1);
                    float y11 = fast_tanh(w10 * c2 + w11 * c3 + bb1);
                    float y   = fast_tanh(w20 * y10 + w21 * y11 + bb2);
                    if ((lane & 3) == 0)
                        out[(size_t)gm * (N >> 2) + (gn >> 2)] = (OutT)y;
                } else {
                    out[(size_t)gm * N + gn] = (OutT)f2bf(c);
                }
            }
        }
    }
#undef STAGE
#undef RDAH
#undef MM
#undef VMW4
#undef BAR
}

// ---------- launch ----------
extern "C" void kernel_launch(void* const* d_in, const int* in_sizes, int n_in,
                              void* d_out, int out_size, void* d_ws, size_t ws_size,
                              hipStream_t stream) {
    constexpr int B   = 16384;
    constexpr int IN  = 4096;
    constexpr int HID = 2048;
    constexpr int CNV = 1024;

    const float* x       = (const float*)d_in[0];
    const void*  mask_ih = d_in[1];
    const void*  mask_hc = d_in[2];
    const float* w_ih    = (const float*)d_in[3];
    const float* b_ih    = (const float*)d_in[4];
    const float* w_hc    = (const float*)d_in[5];
    const float* b_hc    = (const float*)d_in[6];
    const float* w_c1    = (const float*)d_in[7];
    const float* b_c1    = (const float*)d_in[8];
    const float* w_c2    = (const float*)d_in[9];
    const float* b_c2    = (const float*)d_in[10];
    float* out = (float*)d_out;

    // workspace layout (bytes)
    char* ws = (char*)d_ws;
    unsigned short* Xb  = (unsigned short*)(ws);                    // B*IN  bf16
    unsigned short* Wih = (unsigned short*)(ws + 134217728);        // HID*IN bf16
    unsigned short* Whc = (unsigned short*)(ws + 150994944);        // CNV*HID bf16
    unsigned short* Hb  = (unsigned short*)(ws + 155189248);        // B*HID bf16
    int*            flag = (int*)(ws + 222298112);

    detect_mask<<<1, 256, 0, stream>>>((const unsigned char*)mask_ih, flag);

    cast_f32_bf16<<<4096, 256, 0, stream>>>(x, Xb, B * IN);
    mask_cast<<<1024, 256, 0, stream>>>(w_ih, mask_ih, flag, Wih, HID * IN);
    mask_cast<<<256, 256, 0, stream>>>(w_hc, mask_hc, flag, Whc, CNV * HID);

    // GEMM1: [16384,4096] x [2048,4096]^T -> bf16 h ; 64 by x 8 bx = 512 blocks.
    gemm256<unsigned short, false><<<512, 512, 0, stream>>>(
        Xb, Wih, b_ih, Hb, nullptr, nullptr, nullptr, nullptr, HID, IN, 3);

    // GEMM2 + fused double conv: [16384,2048] x [1024,2048]^T -> fp32 [16384,256]
    gemm256<float, true><<<256, 512, 0, stream>>>(
        Hb, Whc, b_hc, out, w_c1, b_c1, w_c2, b_c2, CNV, HID, 2);
}